// Round 1
// baseline (145.422 us; speedup 1.0000x reference)
//
#include <hip/hip_runtime.h>

#define N_LINES 2048
#define N_PIX   131072
#define NCHUNK  8
#define LPC     (N_LINES / NCHUNK)   // 256 lines per chunk
#define THREADS 256
#define PPT     4                    // pixels per thread
#define PIXB    (THREADS * PPT)      // 1024 pixels per block

// ---------------------------------------------------------------------------
// Kernel 1: fold per-line math (exp of params, FWHM quintic, eta) into 5
// pixel-invariant constants per line.
//   profile(d) = Cl * rcp(g2 + d^2) + exp(Ce*d^2 + Kg)
// ---------------------------------------------------------------------------
__global__ __launch_bounds__(THREADS)
void pv_params(const float* __restrict__ lam, const float* __restrict__ la,
               const float* __restrict__ ls, const float* __restrict__ lg,
               float4* __restrict__ pA, float* __restrict__ pB)
{
    int i = blockIdx.x * THREADS + threadIdx.x;
    if (i >= N_LINES) return;
    float sig = __expf(ls[i]);
    float gam = __expf(lg[i]);
    float amp = __expf(la[i]);
    float fg = 2.3548f * sig;
    float fl = 2.0f * gam;
    float fg2 = fg * fg, fl2 = fl * fl;
    float fg3 = fg2 * fg, fl3 = fl2 * fl;
    float fg4 = fg2 * fg2, fl4 = fl2 * fl2;
    float poly = fg4 * fg + 2.69269f * fg4 * fl + 2.42843f * fg3 * fl2
               + 4.47163f * fg2 * fl3 + 0.07842f * fg * fl4 + fl4 * fl;
    float fwhm = powf(poly, 0.2f);
    float fr = fl / fwhm;
    float eta = fr * (1.36603f + fr * (-0.47719f + fr * 0.11116f));
    float Cl = amp * eta * gam * (1.0f / 3.141592654f);
    float Ce = -0.5f / (sig * sig);
    float Cg = amp * (1.0f - eta) / (sig * 2.5066f);
    float Kg = __logf(Cg);
    pA[i] = make_float4(lam[i], gam * gam, Cl, Ce);
    pB[i] = Kg;
}

// ---------------------------------------------------------------------------
// Kernel 2: each block = (1024-pixel tile) x (256-line chunk). Params staged
// in LDS (uniform-address broadcast reads, amortized over 4 pixels/thread).
// Writes per-chunk partial products of (1 - profile).
// ---------------------------------------------------------------------------
__global__ __launch_bounds__(THREADS)
void pv_partial(const float* __restrict__ wl, const float4* __restrict__ pA,
                const float* __restrict__ pB, float* __restrict__ part)
{
    __shared__ float4 sA[LPC];
    __shared__ float  sB[LPC];
    const int t = threadIdx.x;
    const int chunk = blockIdx.y;
    {
        int l = chunk * LPC + t;          // LPC == THREADS == 256
        sA[t] = pA[l];
        sB[t] = pB[l];
    }
    __syncthreads();

    const int p0 = blockIdx.x * PIXB + t;
    float w0 = wl[p0];
    float w1 = wl[p0 + 256];
    float w2 = wl[p0 + 512];
    float w3 = wl[p0 + 768];
    float r0 = 1.0f, r1 = 1.0f, r2 = 1.0f, r3 = 1.0f;

    #pragma unroll 4
    for (int j = 0; j < LPC; ++j) {
        float4 q = sA[j];
        float kg = sB[j];

        float d0 = w0 - q.x, d1 = w1 - q.x, d2 = w2 - q.x, d3 = w3 - q.x;
        float s0 = d0 * d0, s1 = d1 * d1, s2 = d2 * d2, s3 = d3 * d3;

        float i0 = __builtin_amdgcn_rcpf(s0 + q.y);
        float i1 = __builtin_amdgcn_rcpf(s1 + q.y);
        float i2 = __builtin_amdgcn_rcpf(s2 + q.y);
        float i3 = __builtin_amdgcn_rcpf(s3 + q.y);

        float e0 = __expf(fmaf(q.w, s0, kg));
        float e1 = __expf(fmaf(q.w, s1, kg));
        float e2 = __expf(fmaf(q.w, s2, kg));
        float e3 = __expf(fmaf(q.w, s3, kg));

        float t0 = 1.0f - fmaf(q.z, i0, e0);
        float t1 = 1.0f - fmaf(q.z, i1, e1);
        float t2 = 1.0f - fmaf(q.z, i2, e2);
        float t3 = 1.0f - fmaf(q.z, i3, e3);

        r0 *= t0; r1 *= t1; r2 *= t2; r3 *= t3;
    }

    float* dst = part + (size_t)chunk * N_PIX + p0;
    dst[0]   = r0;
    dst[256] = r1;
    dst[512] = r2;
    dst[768] = r3;
}

// ---------------------------------------------------------------------------
// Kernel 3: multiply the 8 chunk partials, apply quadratic modulation.
// float4-vectorized, memory-bound, ~4.7 MB traffic.
// ---------------------------------------------------------------------------
__global__ __launch_bounds__(THREADS)
void pv_combine(const float* __restrict__ wl, const float* __restrict__ part,
                const float* __restrict__ pa, const float* __restrict__ pb,
                const float* __restrict__ pc, float* __restrict__ out)
{
    int i = blockIdx.x * THREADS + threadIdx.x;   // float4 index, N_PIX/4 total
    const float4* w4 = (const float4*)wl;
    float4 w = w4[i];
    float4 r = ((const float4*)part)[i];
    #pragma unroll
    for (int c = 1; c < NCHUNK; ++c) {
        float4 q = ((const float4*)(part + (size_t)c * N_PIX))[i];
        r.x *= q.x; r.y *= q.y; r.z *= q.z; r.w *= q.w;
    }
    float A = pa[0], B = pb[0], C = pc[0];
    float x0 = (w.x - 10500.0f) * (1.0f / 2500.0f);
    float x1 = (w.y - 10500.0f) * (1.0f / 2500.0f);
    float x2 = (w.z - 10500.0f) * (1.0f / 2500.0f);
    float x3 = (w.w - 10500.0f) * (1.0f / 2500.0f);
    float4 o;
    o.x = r.x * (A + x0 * (B + C * x0));
    o.y = r.y * (A + x1 * (B + C * x1));
    o.z = r.z * (A + x2 * (B + C * x2));
    o.w = r.w * (A + x3 * (B + C * x3));
    ((float4*)out)[i] = o;
}

// ---------------------------------------------------------------------------
extern "C" void kernel_launch(void* const* d_in, const int* in_sizes, int n_in,
                              void* d_out, int out_size, void* d_ws, size_t ws_size,
                              hipStream_t stream) {
    const float* wl  = (const float*)d_in[0];
    const float* lam = (const float*)d_in[1];
    const float* la  = (const float*)d_in[2];
    const float* ls  = (const float*)d_in[3];
    const float* lg  = (const float*)d_in[4];
    const float* pa  = (const float*)d_in[5];
    const float* pb  = (const float*)d_in[6];
    const float* pc  = (const float*)d_in[7];

    char* ws = (char*)d_ws;
    float4* pA  = (float4*)ws;                 // 2048 * 16 B = 32768 B
    float*  pB  = (float*)(ws + 32768);        // 2048 *  4 B =  8192 B
    float* part = (float*)(ws + 40960);        // 8 * 131072 * 4 B = 4 MB
    float* out  = (float*)d_out;

    pv_params<<<N_LINES / THREADS, THREADS, 0, stream>>>(lam, la, ls, lg, pA, pB);

    dim3 grid2(N_PIX / PIXB, NCHUNK);          // (128, 8) = 1024 blocks
    pv_partial<<<grid2, THREADS, 0, stream>>>(wl, pA, pB, part);

    pv_combine<<<N_PIX / 4 / THREADS, THREADS, 0, stream>>>(wl, part, pa, pb, pc, out);
}

// Round 2
// 71.520 us; speedup vs baseline: 2.0333x; 2.0333x over previous
//
#include <hip/hip_runtime.h>

#define N_LINES 2048
#define N_PIX   131072
#define THREADS 256
#define SMAX    512          // LDS line-tile capacity (way above worst-case window count)
#define WINDOW  6.0f         // truncation half-width in Angstroms; tail error ~7e-4 << 2e-2

// ---------------------------------------------------------------------------
// Fully fused pseudo-Voigt emulator.
// Per block of 256 pixels (span ~2.74 A):
//   1. wave-uniform binary search on sorted lam_centers for lines within
//      [wmin - WINDOW, wmax + WINDOW]  (~22 lines expected)
//   2. cooperatively fold per-line math into 5 constants in LDS:
//        profile(d) = Cl * rcp(g2 + d^2) + exp(Ce*d^2 + Kg)
//   3. per-pixel product over the windowed lines
//   4. quadratic modulation, store
// Lines outside the window contribute < ~1.5e-3 total (Lorentzian 1/d^2 tails,
// density 1.53/A, mean C=amp*eta*gam/pi ~ 1.3e-3); Gaussian tails ~18 sigma = 0.
// ---------------------------------------------------------------------------
__global__ __launch_bounds__(THREADS)
void pv_fused(const float* __restrict__ wl,  const float* __restrict__ lam,
              const float* __restrict__ la,  const float* __restrict__ ls,
              const float* __restrict__ lg,  const float* __restrict__ pa,
              const float* __restrict__ pb,  const float* __restrict__ pc,
              float* __restrict__ out)
{
    __shared__ float4 sA[SMAX];
    __shared__ float  sB[SMAX];
    const int t = threadIdx.x;
    const int p = blockIdx.x * THREADS + t;
    const float w    = wl[p];
    const float wmin = wl[blockIdx.x * THREADS];
    const float wmax = wl[blockIdx.x * THREADS + (THREADS - 1)];
    const float loV  = wmin - WINDOW;
    const float hiV  = wmax + WINDOW;

    // wave-uniform binary searches (lower bounds)
    int lo = 0, hi = N_LINES;
    while (lo < hi) { int m = (lo + hi) >> 1; if (lam[m] < loV) lo = m + 1; else hi = m; }
    const int lo0 = lo;
    hi = N_LINES;
    while (lo < hi) { int m = (lo + hi) >> 1; if (lam[m] < hiV) lo = m + 1; else hi = m; }
    const int hi0 = lo;

    float r = 1.0f;
    for (int base = lo0; base < hi0; base += SMAX) {
        const int nl = min(hi0 - base, SMAX);
        __syncthreads();                      // protect LDS reuse across tiles
        for (int l = t; l < nl; l += THREADS) {
            const int i = base + l;
            float sig = __expf(ls[i]);
            float gam = __expf(lg[i]);
            float amp = __expf(la[i]);
            float fg = 2.3548f * sig;
            float fl = 2.0f * gam;
            float fg2 = fg * fg, fl2 = fl * fl;
            float fg3 = fg2 * fg, fl3 = fl2 * fl;
            float fg4 = fg2 * fg2, fl4 = fl2 * fl2;
            float poly = fg4 * fg + 2.69269f * fg4 * fl + 2.42843f * fg3 * fl2
                       + 4.47163f * fg2 * fl3 + 0.07842f * fg * fl4 + fl4 * fl;
            float fwhm = __expf(0.2f * __logf(poly));        // poly^0.2
            float fr = fl * __builtin_amdgcn_rcpf(fwhm);
            float eta = fr * (1.36603f + fr * (-0.47719f + fr * 0.11116f));
            float Cl = amp * eta * gam * (1.0f / 3.141592654f);
            float Ce = -0.5f / (sig * sig);
            float Kg = __logf(amp * (1.0f - eta) / (sig * 2.5066f));
            sA[l] = make_float4(lam[i], gam * gam, Cl, Ce);
            sB[l] = Kg;
        }
        __syncthreads();

        for (int j = 0; j < nl; ++j) {        // LDS broadcast reads, conflict-free
            float4 q = sA[j];
            float kg = sB[j];
            float d = w - q.x;
            float s = d * d;
            float lor = q.z * __builtin_amdgcn_rcpf(s + q.y);
            float gau = __expf(fmaf(q.w, s, kg));
            r *= 1.0f - (lor + gau);
        }
    }

    const float A = pa[0], B = pb[0], C = pc[0];
    const float x = (w - 10500.0f) * (1.0f / 2500.0f);
    out[p] = r * (A + x * (B + C * x));
}

// ---------------------------------------------------------------------------
extern "C" void kernel_launch(void* const* d_in, const int* in_sizes, int n_in,
                              void* d_out, int out_size, void* d_ws, size_t ws_size,
                              hipStream_t stream) {
    const float* wl  = (const float*)d_in[0];
    const float* lam = (const float*)d_in[1];
    const float* la  = (const float*)d_in[2];
    const float* ls  = (const float*)d_in[3];
    const float* lg  = (const float*)d_in[4];
    const float* pa  = (const float*)d_in[5];
    const float* pb  = (const float*)d_in[6];
    const float* pc  = (const float*)d_in[7];
    float* out = (float*)d_out;

    pv_fused<<<N_PIX / THREADS, THREADS, 0, stream>>>(wl, lam, la, ls, lg, pa, pb, pc, out);
}

// Round 3
// 69.504 us; speedup vs baseline: 2.0923x; 1.0290x over previous
//
#include <hip/hip_runtime.h>

#define N_LINES 2048
#define N_PIX   131072
#define THREADS 256
#define SMAX    512          // LDS line-tile capacity (worst-case window count ~50)
#define WINDOW  6.0f         // truncation half-width; tail error ~1e-3 << 2e-2 threshold

// ---------------------------------------------------------------------------
// Fused pseudo-Voigt emulator, round 3.
// Change vs R2: the per-block line-range search is a 2-round ballot fan-out
// (64-lane stride-32 sample -> 32-wide bracket -> 32-lane resolve) instead of
// 2 x 11 dependent binary-search loads. Search latency ~500 cyc vs ~4400.
// Occupancy is capped at 2 waves/SIMD (1 px/thread over 131072 px), so serial
// latency in the prologue is what shows up on the wall clock.
// ---------------------------------------------------------------------------
__global__ __launch_bounds__(THREADS)
void pv_fused(const float* __restrict__ wl,  const float* __restrict__ lam,
              const float* __restrict__ la,  const float* __restrict__ ls,
              const float* __restrict__ lg,  const float* __restrict__ pa,
              const float* __restrict__ pb,  const float* __restrict__ pc,
              float* __restrict__ out)
{
    __shared__ float4 sA[SMAX];
    __shared__ float  sB[SMAX];
    const int t = threadIdx.x;
    const int p = blockIdx.x * THREADS + t;

    // Issue every independent load before the search latency chain.
    const float w    = wl[p];
    const float wmin = wl[blockIdx.x * THREADS];
    const float wmax = wl[blockIdx.x * THREADS + (THREADS - 1)];
    const float A = pa[0], B = pb[0], C = pc[0];

    const float loV = wmin - WINDOW;
    const float hiV = wmax + WINDOW;

    // ---- 2-round ballot fan-out search (wave-uniform result) ----
    // lower_bound(lam, loV) -> lo0 ; lower_bound(lam, hiV) -> hi0
    const int lane = t & 63;
    // Round A: sample lam at stride 32 (covers all 2048 with 64 lanes).
    float vA = lam[lane << 5];
    unsigned long long bLo = __ballot(vA < loV);
    unsigned long long bHi = __ballot(vA < hiV);
    int cLo = __builtin_popcountll(bLo);     // lam[32*(cLo-1)] < loV <= lam[32*cLo]
    int cHi = __builtin_popcountll(bHi);
    // Round B: lanes 0-31 resolve the lo bracket, lanes 32-63 the hi bracket.
    int j = lane & 31;
    int cSel = (lane < 64 / 2) ? cLo : cHi;
    float vSel = (lane < 32) ? loV : hiV;
    int idx = 32 * (cSel - 1) + 1 + j;
    idx = max(0, min(idx, N_LINES - 1));
    unsigned long long bB = __ballot(lam[idx] < vSel);
    int cBlo = __builtin_popcountll(bB & 0xFFFFFFFFull);
    int cBhi = __builtin_popcountll(bB >> 32);
    int lo0 = (cLo == 0) ? 0 : min(N_LINES, 32 * (cLo - 1) + 1 + cBlo);
    int hi0 = (cHi == 0) ? 0 : min(N_LINES, 32 * (cHi - 1) + 1 + cBhi);

    float r = 1.0f;
    for (int base = lo0; base < hi0; base += SMAX) {
        const int nl = min(hi0 - base, SMAX);
        __syncthreads();                      // protect LDS reuse across tiles
        for (int l = t; l < nl; l += THREADS) {
            const int i = base + l;
            float sig = __expf(ls[i]);
            float gam = __expf(lg[i]);
            float amp = __expf(la[i]);
            float fg = 2.3548f * sig;
            float fl = 2.0f * gam;
            float fg2 = fg * fg, fl2 = fl * fl;
            float fg3 = fg2 * fg, fl3 = fl2 * fl;
            float fg4 = fg2 * fg2, fl4 = fl2 * fl2;
            float poly = fg4 * fg + 2.69269f * fg4 * fl + 2.42843f * fg3 * fl2
                       + 4.47163f * fg2 * fl3 + 0.07842f * fg * fl4 + fl4 * fl;
            float fwhm = __expf(0.2f * __logf(poly));        // poly^0.2
            float fr = fl * __builtin_amdgcn_rcpf(fwhm);
            float eta = fr * (1.36603f + fr * (-0.47719f + fr * 0.11116f));
            float Cl = amp * eta * gam * (1.0f / 3.141592654f);
            float Ce = -0.5f / (sig * sig);
            float Kg = __logf(amp * (1.0f - eta) / (sig * 2.5066f));
            sA[l] = make_float4(lam[i], gam * gam, Cl, Ce);
            sB[l] = Kg;
        }
        __syncthreads();

        #pragma unroll 2
        for (int jj = 0; jj < nl; ++jj) {     // LDS broadcast reads, conflict-free
            float4 q = sA[jj];
            float kg = sB[jj];
            float d = w - q.x;
            float s = d * d;
            float lor = q.z * __builtin_amdgcn_rcpf(s + q.y);
            float gau = __expf(fmaf(q.w, s, kg));
            r *= 1.0f - (lor + gau);
        }
    }

    const float x = (w - 10500.0f) * (1.0f / 2500.0f);
    out[p] = r * (A + x * (B + C * x));
}

// ---------------------------------------------------------------------------
extern "C" void kernel_launch(void* const* d_in, const int* in_sizes, int n_in,
                              void* d_out, int out_size, void* d_ws, size_t ws_size,
                              hipStream_t stream) {
    const float* wl  = (const float*)d_in[0];
    const float* lam = (const float*)d_in[1];
    const float* la  = (const float*)d_in[2];
    const float* ls  = (const float*)d_in[3];
    const float* lg  = (const float*)d_in[4];
    const float* pa  = (const float*)d_in[5];
    const float* pb  = (const float*)d_in[6];
    const float* pc  = (const float*)d_in[7];
    float* out = (float*)d_out;

    pv_fused<<<N_PIX / THREADS, THREADS, 0, stream>>>(wl, lam, la, ls, lg, pa, pb, pc, out);
}